// Round 1
// baseline (106.760 us; speedup 1.0000x reference)
//
#include <hip/hip_runtime.h>
#include <hip/hip_bf16.h>

#define B_N 2048
#define D_V 8
#define F_D 256

typedef __attribute__((ext_vector_type(8))) short short8;
typedef __attribute__((ext_vector_type(4))) float floatx4;

__device__ inline unsigned short f2bf(float f) {
    __hip_bfloat16 h = __float2bfloat16(f);
    return *reinterpret_cast<unsigned short*>(&h);
}

__device__ inline float wave_reduce_sum(float v) {
    #pragma unroll
    for (int off = 1; off < 64; off <<= 1)
        v += __shfl_xor(v, off, 64);
    return v;
}

// ---------------------------------------------------------------------------
// Kernel 1: normalize each (b,d) row of 256 floats; write bf16 zn in [d][b][f]
// layout (d-major so the per-view Gram kernels get contiguous matrices).
// One wave per row; lane holds exactly one float4.
// ---------------------------------------------------------------------------
__global__ void norm_kernel(const float* __restrict__ z,
                            unsigned short* __restrict__ zn) {
    int wave = (blockIdx.x * blockDim.x + threadIdx.x) >> 6;  // row = b*8+d
    int lane = threadIdx.x & 63;
    const float4* zp = (const float4*)(z + (size_t)wave * F_D);
    float4 v = zp[lane];
    float ss = v.x * v.x + v.y * v.y + v.z * v.z + v.w * v.w;
    ss = wave_reduce_sum(ss);
    float inv = 1.0f / fmaxf(sqrtf(ss), 1e-12f);
    int b = wave >> 3, d = wave & 7;
    unsigned short* op = zn + (size_t)d * (B_N * F_D) + (size_t)b * F_D + lane * 4;
    ushort4 o;
    o.x = f2bf(v.x * inv);
    o.y = f2bf(v.y * inv);
    o.z = f2bf(v.z * inv);
    o.w = f2bf(v.w * inv);
    *(ushort4*)op = o;
}

// ---------------------------------------------------------------------------
// Kernel 2: pos[b] = sum_{d!=e} exp(2*dot(zn[b,d], zn[b,e]))
// One wave handles 2 samples: 16 rows = [s0 views 0..7 | s1 views 0..7].
// Gram via MFMA with a_frag == b_frag (identical layouts for Z·Z^T).
// ---------------------------------------------------------------------------
__global__ void pos_kernel(const unsigned short* __restrict__ zn,
                           float* __restrict__ pos) {
    int gw = (blockIdx.x * blockDim.x + threadIdx.x) >> 6;  // wave id 0..1023
    int lane = threadIdx.x & 63;
    int q = lane >> 4, li = lane & 15;
    int s0 = gw * 2;
    int b = s0 + (li >> 3), d = li & 7;   // row li of the 16x16 A tile
    const unsigned short* rowp = zn + (size_t)d * (B_N * F_D) + (size_t)b * F_D;
    short8 a[8];
    #pragma unroll
    for (int kk = 0; kk < 8; kk++)
        a[kk] = *(const short8*)(rowp + kk * 32 + q * 8);
    floatx4 acc = {0.f, 0.f, 0.f, 0.f};
    #pragma unroll
    for (int kk = 0; kk < 8; kk++)
        acc = __builtin_amdgcn_mfma_f32_16x16x32_bf16(a[kk], a[kk], acc, 0, 0, 0);
    // C/D layout: col = lane&15, row = q*4 + r
    float p0 = 0.f, p1 = 0.f;
    #pragma unroll
    for (int r = 0; r < 4; r++) {
        int row = q * 4 + r, col = li;
        bool same_sample = (row >> 3) == (col >> 3);
        if (same_sample && row != col) {
            float e = __expf(2.0f * acc[r]);
            if (row < 8) p0 += e; else p1 += e;
        }
    }
    p0 = wave_reduce_sum(p0);
    p1 = wave_reduce_sum(p1);
    if (lane == 0) { pos[s0] = p0; pos[s0 + 1] = p1; }
}

// ---------------------------------------------------------------------------
// Kernel 3: negsum[b] += sum_d sum_{c!=b} exp(2*dot(zn[b,d], zn[c,d]))
// Grid: (16 row-strips of 128, 4 col-chunks of 512, 8 views). Block 256 thr.
// Each wave: 32 rows (two 16-row MFMA sets), A (K=256) fully in registers.
// B column-tiles staged in LDS, padded stride 264 (2-way read alias = free).
// ---------------------------------------------------------------------------
#define BCOLS 64
#define LSTRIDE 264

__global__ void neg_kernel(const unsigned short* __restrict__ zn,
                           float* __restrict__ negsum) {
    __shared__ __align__(16) unsigned short Bs[BCOLS * LSTRIDE];
    const int d = blockIdx.z;
    const unsigned short* Z = zn + (size_t)d * (B_N * F_D);
    int tid = threadIdx.x;
    int w = tid >> 6, lane = tid & 63;
    int q = lane >> 4, li = lane & 15;
    int r0 = blockIdx.x * 128 + w * 32;   // set0: r0..r0+15, set1: r0+16..r0+31
    int c_base = blockIdx.y * 512;

    short8 a0[8], a1[8];
    #pragma unroll
    for (int kk = 0; kk < 8; kk++) {
        a0[kk] = *(const short8*)(Z + (size_t)(r0 + li) * F_D + kk * 32 + q * 8);
        a1[kk] = *(const short8*)(Z + (size_t)(r0 + 16 + li) * F_D + kk * 32 + q * 8);
    }
    float rs0[4] = {0.f, 0.f, 0.f, 0.f}, rs1[4] = {0.f, 0.f, 0.f, 0.f};

    for (int stage = 0; stage < 512 / BCOLS; ++stage) {
        int c0 = c_base + stage * BCOLS;
        __syncthreads();
        // stage 64 rows x 256 elems into LDS: 2048 16B-chunks, 8 per thread
        #pragma unroll
        for (int it = 0; it < 8; ++it) {
            int idx = it * 256 + tid;
            int row = idx >> 5;       // 0..63
            int kc = idx & 31;        // 16B chunk within row
            *(short8*)(&Bs[row * LSTRIDE + kc * 8]) =
                *(const short8*)(Z + (size_t)(c0 + row) * F_D + kc * 8);
        }
        __syncthreads();
        #pragma unroll
        for (int ct = 0; ct < BCOLS / 16; ++ct) {
            short8 bf[8];
            #pragma unroll
            for (int kk = 0; kk < 8; kk++)
                bf[kk] = *(const short8*)(&Bs[(ct * 16 + li) * LSTRIDE + kk * 32 + q * 8]);
            floatx4 acc0 = {0.f, 0.f, 0.f, 0.f}, acc1 = {0.f, 0.f, 0.f, 0.f};
            #pragma unroll
            for (int kk = 0; kk < 8; kk++) {
                acc0 = __builtin_amdgcn_mfma_f32_16x16x32_bf16(a0[kk], bf[kk], acc0, 0, 0, 0);
                acc1 = __builtin_amdgcn_mfma_f32_16x16x32_bf16(a1[kk], bf[kk], acc1, 0, 0, 0);
            }
            int gc0 = c0 + ct * 16;
            bool diag0 = (gc0 == r0);
            bool diag1 = (gc0 == r0 + 16);
            #pragma unroll
            for (int r = 0; r < 4; ++r) {
                float e0 = __expf(2.0f * acc0[r]);
                float e1 = __expf(2.0f * acc1[r]);
                int rloc = q * 4 + r;
                if (!(diag0 && li == rloc)) rs0[r] += e0;
                if (!(diag1 && li == rloc)) rs1[r] += e1;
            }
        }
    }
    // reduce row sums across the 16 column-lanes (low 4 bits of lane)
    #pragma unroll
    for (int off = 1; off < 16; off <<= 1) {
        #pragma unroll
        for (int r = 0; r < 4; r++) {
            rs0[r] += __shfl_xor(rs0[r], off, 64);
            rs1[r] += __shfl_xor(rs1[r], off, 64);
        }
    }
    if (li == 0) {
        #pragma unroll
        for (int r = 0; r < 4; r++) {
            atomicAdd(&negsum[r0 + q * 4 + r], rs0[r]);
            atomicAdd(&negsum[r0 + 16 + q * 4 + r], rs1[r]);
        }
    }
}

// ---------------------------------------------------------------------------
// Kernel 4: logits = pos/(pos+neg); loss = max + log(sum exp(l-max)) - mean(l)
// ---------------------------------------------------------------------------
__global__ void final_kernel(const float* __restrict__ pos,
                             const float* __restrict__ negsum,
                             float* __restrict__ out) {
    __shared__ float red[256];
    int t = threadIdx.x;
    float vals[8];
    float lmax = -1e30f;
    #pragma unroll
    for (int i = 0; i < 8; i++) {
        int idx = t * 8 + i;
        float p = pos[idx];
        float n = negsum[idx] * (1.0f / (float)(B_N - 1));
        float l = p / (p + n);
        vals[i] = l;
        lmax = fmaxf(lmax, l);
    }
    red[t] = lmax; __syncthreads();
    for (int s = 128; s > 0; s >>= 1) {
        if (t < s) red[t] = fmaxf(red[t], red[t + s]);
        __syncthreads();
    }
    float m = red[0]; __syncthreads();
    float se = 0.f, sl = 0.f;
    #pragma unroll
    for (int i = 0; i < 8; i++) { se += expf(vals[i] - m); sl += vals[i]; }
    red[t] = se; __syncthreads();
    for (int s = 128; s > 0; s >>= 1) {
        if (t < s) red[t] += red[t + s];
        __syncthreads();
    }
    float S = red[0]; __syncthreads();
    red[t] = sl; __syncthreads();
    for (int s = 128; s > 0; s >>= 1) {
        if (t < s) red[t] += red[t + s];
        __syncthreads();
    }
    if (t == 0) out[0] = m + logf(S) - red[0] / (float)B_N;
}

extern "C" void kernel_launch(void* const* d_in, const int* in_sizes, int n_in,
                              void* d_out, int out_size, void* d_ws, size_t ws_size,
                              hipStream_t stream) {
    const float* z = (const float*)d_in[0];
    float* out = (float*)d_out;
    unsigned short* zn = (unsigned short*)d_ws;                       // 8 MB bf16
    float* negsum = (float*)((char*)d_ws + (size_t)D_V * B_N * F_D * 2);
    float* pos = negsum + B_N;

    hipMemsetAsync(negsum, 0, B_N * sizeof(float), stream);
    norm_kernel<<<dim3(4096), 256, 0, stream>>>(z, zn);
    pos_kernel<<<dim3(256), 256, 0, stream>>>(zn, pos);
    neg_kernel<<<dim3(16, 4, 8), 256, 0, stream>>>(zn, negsum);
    final_kernel<<<1, 256, 0, stream>>>(pos, negsum, out);
}

// Round 2
// 95.860 us; speedup vs baseline: 1.1137x; 1.1137x over previous
//
#include <hip/hip_runtime.h>
#include <hip/hip_bf16.h>

#define B_N 2048
#define D_V 8
#define F_D 256
#define TILE 128
#define BC 64
#define LSTR 264   // padded LDS row stride (shorts); 264*2B=528B -> bank-conflict-free

typedef __attribute__((ext_vector_type(8))) short short8;
typedef __attribute__((ext_vector_type(4))) float floatx4;

__device__ inline unsigned short f2bf(float f) {
    __hip_bfloat16 h = __float2bfloat16(f);
    return *reinterpret_cast<unsigned short*>(&h);
}

__device__ inline float wave_reduce_sum(float v) {
    #pragma unroll
    for (int off = 1; off < 64; off <<= 1)
        v += __shfl_xor(v, off, 64);
    return v;
}

// ---------------------------------------------------------------------------
// Kernel 1: normalize each (b,d) row of 256 floats; write bf16 zn in [d][b][f]
// layout. One wave per row. Also zero-inits ns8[8][2048] (replaces memset).
// ---------------------------------------------------------------------------
__global__ void norm_kernel(const float* __restrict__ z,
                            unsigned short* __restrict__ zn,
                            float* __restrict__ ns8) {
    int gid = blockIdx.x * blockDim.x + threadIdx.x;
    if (gid < D_V * B_N) ns8[gid] = 0.0f;
    int wave = gid >> 6;  // row = b*8+d
    int lane = threadIdx.x & 63;
    const float4* zp = (const float4*)(z + (size_t)wave * F_D);
    float4 v = zp[lane];
    float ss = v.x * v.x + v.y * v.y + v.z * v.z + v.w * v.w;
    ss = wave_reduce_sum(ss);
    float inv = 1.0f / fmaxf(sqrtf(ss), 1e-12f);
    int b = wave >> 3, d = wave & 7;
    unsigned short* op = zn + (size_t)d * (B_N * F_D) + (size_t)b * F_D + lane * 4;
    ushort4 o;
    o.x = f2bf(v.x * inv);
    o.y = f2bf(v.y * inv);
    o.z = f2bf(v.z * inv);
    o.w = f2bf(v.w * inv);
    *(ushort4*)op = o;
}

// ---------------------------------------------------------------------------
// Kernel 2: pos[b] = sum_{d!=e} exp(2*dot(zn[b,d], zn[b,e]))
// One wave handles 2 samples: 16 rows = [s0 views 0..7 | s1 views 0..7].
// ---------------------------------------------------------------------------
__global__ void pos_kernel(const unsigned short* __restrict__ zn,
                           float* __restrict__ pos) {
    int gw = (blockIdx.x * blockDim.x + threadIdx.x) >> 6;
    int lane = threadIdx.x & 63;
    int q = lane >> 4, li = lane & 15;
    int s0 = gw * 2;
    int b = s0 + (li >> 3), d = li & 7;
    const unsigned short* rowp = zn + (size_t)d * (B_N * F_D) + (size_t)b * F_D;
    short8 a[8];
    #pragma unroll
    for (int kk = 0; kk < 8; kk++)
        a[kk] = *(const short8*)(rowp + kk * 32 + q * 8);
    floatx4 acc = {0.f, 0.f, 0.f, 0.f};
    #pragma unroll
    for (int kk = 0; kk < 8; kk++)
        acc = __builtin_amdgcn_mfma_f32_16x16x32_bf16(a[kk], a[kk], acc, 0, 0, 0);
    float p0 = 0.f, p1 = 0.f;
    #pragma unroll
    for (int r = 0; r < 4; r++) {
        int row = q * 4 + r, col = li;
        bool same_sample = (row >> 3) == (col >> 3);
        if (same_sample && row != col) {
            float e = __expf(2.0f * acc[r]);
            if (row < 8) p0 += e; else p1 += e;
        }
    }
    p0 = wave_reduce_sum(p0);
    p1 = wave_reduce_sum(p1);
    if (lane == 0) { pos[s0] = p0; pos[s0 + 1] = p1; }
}

// ---------------------------------------------------------------------------
// Kernel 3 (symmetric-halved): per view d, for upper-triangle 128x128 tiles
// (i<=j) of S = exp(2 * Z Z^T): row-sums -> ns8[d][i*128+..]; for off-diag
// tiles also col-sums -> ns8[d][j*128+..] (covers the mirrored tile).
// Block = 128 threads (2 waves); each wave owns 64 A-rows (4 MFMA row-sets,
// K=256 resident in 128 VGPRs). B staged in LDS 64 cols at a time.
// ---------------------------------------------------------------------------
__global__ __launch_bounds__(128, 2)
void neg_kernel(const unsigned short* __restrict__ zn,
                float* __restrict__ ns8) {
    __shared__ __align__(16) unsigned short Bs[BC * LSTR];  // 33 KB
    __shared__ float csred[2][TILE];
    const int d = blockIdx.y;
    int trem = blockIdx.x;            // 0..135 -> (i,j), i<=j
    int i = 0;
    while (trem >= 16 - i) { trem -= 16 - i; ++i; }
    const int j = i + trem;
    const bool diag = (i == j);
    const unsigned short* Z = zn + (size_t)d * (B_N * F_D);
    int tid = threadIdx.x, w = tid >> 6, lane = tid & 63;
    int q = lane >> 4, li = lane & 15;
    int r0 = i * TILE + w * 64;       // this wave's 64 A-rows

    short8 a[4][8];
    #pragma unroll
    for (int s = 0; s < 4; s++)
        #pragma unroll
        for (int kk = 0; kk < 8; kk++)
            a[s][kk] = *(const short8*)(Z + (size_t)(r0 + s * 16 + li) * F_D + kk * 32 + q * 8);

    float rs[4][4];
    #pragma unroll
    for (int s = 0; s < 4; s++)
        #pragma unroll
        for (int r = 0; r < 4; r++) rs[s][r] = 0.f;
    float cacc[2] = {0.f, 0.f};

    for (int stage = 0; stage < 2; ++stage) {
        int c0 = j * TILE + stage * BC;
        __syncthreads();
        // stage 64 rows x 256 shorts: 2048 16B-chunks, 16 per thread
        #pragma unroll
        for (int it = 0; it < 16; ++it) {
            int idx = it * 128 + tid;
            int row = idx >> 5, kc = idx & 31;
            *(short8*)(&Bs[row * LSTR + kc * 8]) =
                *(const short8*)(Z + (size_t)(c0 + row) * F_D + kc * 8);
        }
        __syncthreads();
        #pragma unroll
        for (int ct = 0; ct < 4; ++ct) {
            short8 bf[8];
            #pragma unroll
            for (int kk = 0; kk < 8; kk++)
                bf[kk] = *(const short8*)(&Bs[(ct * 16 + li) * LSTR + kk * 32 + q * 8]);
            floatx4 acc[4];
            #pragma unroll
            for (int s = 0; s < 4; s++) acc[s] = (floatx4){0.f, 0.f, 0.f, 0.f};
            #pragma unroll
            for (int kk = 0; kk < 8; kk++)
                #pragma unroll
                for (int s = 0; s < 4; s++)
                    acc[s] = __builtin_amdgcn_mfma_f32_16x16x32_bf16(a[s][kk], bf[kk], acc[s], 0, 0, 0);
            // C/D layout: col = li, row(within set) = q*4 + r
            int gcol = c0 + ct * 16 + li;
            float csum = 0.f;
            #pragma unroll
            for (int s = 0; s < 4; s++) {
                #pragma unroll
                for (int r = 0; r < 4; r++) {
                    float e = __expf(2.0f * acc[s][r]);
                    int grow = r0 + s * 16 + q * 4 + r;
                    e = (diag && grow == gcol) ? 0.f : e;
                    rs[s][r] += e;
                    csum += e;
                }
            }
            // colsum over this wave's 64 rows: reduce across q-groups
            csum += __shfl_xor(csum, 16, 64);
            csum += __shfl_xor(csum, 32, 64);
            // holder: lane (ct*16+li) keeps col (stage*64 + ct*16 + li)
            if (q == ct) cacc[stage] += csum;
        }
    }

    // row sums: reduce across the 16 column-lanes
    #pragma unroll
    for (int off = 1; off < 16; off <<= 1)
        #pragma unroll
        for (int s = 0; s < 4; s++)
            #pragma unroll
            for (int r = 0; r < 4; r++)
                rs[s][r] += __shfl_xor(rs[s][r], off, 64);
    if (li == 0) {
        #pragma unroll
        for (int s = 0; s < 4; s++)
            #pragma unroll
            for (int r = 0; r < 4; r++)
                atomicAdd(&ns8[d * B_N + r0 + s * 16 + q * 4 + r], rs[s][r]);
    }

    // col sums: combine the 2 waves in LDS, then one atomic per column
    csred[w][lane] = cacc[0];
    csred[w][64 + lane] = cacc[1];
    __syncthreads();
    if (!diag && tid < TILE) {
        float v = csred[0][tid] + csred[1][tid];
        atomicAdd(&ns8[d * B_N + j * TILE + tid], v);
    }
}

// ---------------------------------------------------------------------------
// Kernel 4: neg[b] = sum_d ns8[d][b] / (B-1); logits = pos/(pos+neg);
// loss = max + log(sum exp(l-max)) - mean(l)
// ---------------------------------------------------------------------------
__global__ void final_kernel(const float* __restrict__ pos,
                             const float* __restrict__ ns8,
                             float* __restrict__ out) {
    __shared__ float red[256];
    int t = threadIdx.x;
    float vals[8];
    float lmax = -1e30f;
    #pragma unroll
    for (int i = 0; i < 8; i++) {
        int idx = t * 8 + i;
        float nsum = 0.f;
        #pragma unroll
        for (int d = 0; d < D_V; d++) nsum += ns8[d * B_N + idx];
        float p = pos[idx];
        float n = nsum * (1.0f / (float)(B_N - 1));
        float l = p / (p + n);
        vals[i] = l;
        lmax = fmaxf(lmax, l);
    }
    red[t] = lmax; __syncthreads();
    for (int s = 128; s > 0; s >>= 1) {
        if (t < s) red[t] = fmaxf(red[t], red[t + s]);
        __syncthreads();
    }
    float m = red[0]; __syncthreads();
    float se = 0.f, sl = 0.f;
    #pragma unroll
    for (int i = 0; i < 8; i++) { se += expf(vals[i] - m); sl += vals[i]; }
    red[t] = se; __syncthreads();
    for (int s = 128; s > 0; s >>= 1) {
        if (t < s) red[t] += red[t + s];
        __syncthreads();
    }
    float S = red[0]; __syncthreads();
    red[t] = sl; __syncthreads();
    for (int s = 128; s > 0; s >>= 1) {
        if (t < s) red[t] += red[t + s];
        __syncthreads();
    }
    if (t == 0) out[0] = m + logf(S) - red[0] / (float)B_N;
}

extern "C" void kernel_launch(void* const* d_in, const int* in_sizes, int n_in,
                              void* d_out, int out_size, void* d_ws, size_t ws_size,
                              hipStream_t stream) {
    const float* z = (const float*)d_in[0];
    float* out = (float*)d_out;
    unsigned short* zn = (unsigned short*)d_ws;                        // 8 MB bf16
    float* ns8 = (float*)((char*)d_ws + (size_t)D_V * B_N * F_D * 2);  // 64 KB
    float* pos = ns8 + D_V * B_N;                                      // 8 KB

    norm_kernel<<<dim3(4096), 256, 0, stream>>>(z, zn, ns8);
    pos_kernel<<<dim3(256), 256, 0, stream>>>(zn, pos);
    neg_kernel<<<dim3(136, 8), 128, 0, stream>>>(zn, ns8);
    final_kernel<<<1, 256, 0, stream>>>(pos, ns8, out);
}